// Round 1
// baseline (284.276 us; speedup 1.0000x reference)
//
#include <hip/hip_runtime.h>
#include <math.h>

#define Bn 8
#define Cn 512
#define Kn 64
#define C4n 128
#define Nn 4096

// ---------------------------------------------------------------------------
// pv[b,c,k] = sum_c' y[b,k,c'] * wv[c,c'] + bv[c]   (for y1 and y2)
__global__ __launch_bounds__(256) void proj_pv_kernel(
    const float* __restrict__ y1, const float* __restrict__ y2,
    const float* __restrict__ wv, const float* __restrict__ bv,
    float* __restrict__ pv1, float* __restrict__ pv2)
{
    int idx = blockIdx.x * 256 + threadIdx.x;   // 0 .. 2*B*C*K-1
    int sel = idx >> 18;
    int r = idx & 262143;
    int k = r & 63;
    int c = (r >> 6) & 511;
    int b = r >> 15;
    const float* y = sel ? y2 : y1;
    float* pv = sel ? pv2 : pv1;
    const float* yr = y + (size_t)(b * Kn + k) * Cn;
    const float* wr = wv + (size_t)c * Cn;
    float acc = bv[c];
    #pragma unroll 4
    for (int cc = 0; cc < Cn; cc += 4) {
        float4 yv = *(const float4*)(yr + cc);
        float4 wv4 = *(const float4*)(wr + cc);
        acc += yv.x * wv4.x + yv.y * wv4.y + yv.z * wv4.z + yv.w * wv4.w;
    }
    pv[(size_t)(b * Cn + c) * Kn + k] = acc;
}

// ---------------------------------------------------------------------------
// kkt[b,d,k] = sum_c y2[b,k,c] * wk[d,c] + bk[d]   (transposed store)
__global__ __launch_bounds__(256) void proj_kkt_kernel(
    const float* __restrict__ y2, const float* __restrict__ wk,
    const float* __restrict__ bk, float* __restrict__ kkt)
{
    int idx = blockIdx.x * 256 + threadIdx.x;   // 0 .. B*C4*K-1
    int k = idx & 63;
    int d = (idx >> 6) & 127;
    int b = idx >> 13;
    const float* yr = y2 + (size_t)(b * Kn + k) * Cn;
    const float* wr = wk + (size_t)d * Cn;
    float acc = bk[d];
    #pragma unroll 4
    for (int cc = 0; cc < Cn; cc += 4) {
        float4 yv = *(const float4*)(yr + cc);
        float4 wv4 = *(const float4*)(wr + cc);
        acc += yv.x * wv4.x + yv.y * wv4.y + yv.z * wv4.z + yv.w * wv4.w;
    }
    kkt[(size_t)(b * C4n + d) * Kn + k] = acc;
}

// ---------------------------------------------------------------------------
// Mc[b,c,k] = sum_d kkt[b,d,k] * wq[d,c]
__global__ __launch_bounds__(256) void proj_M_kernel(
    const float* __restrict__ kkt, const float* __restrict__ wq,
    float* __restrict__ Mc)
{
    int idx = blockIdx.x * 256 + threadIdx.x;   // 0 .. B*C*K-1
    int k = idx & 63;
    int c = (idx >> 6) & 511;
    int b = idx >> 15;
    const float* kb_ = kkt + (size_t)b * C4n * Kn + k;
    float acc = 0.f;
    #pragma unroll 8
    for (int d = 0; d < C4n; ++d)
        acc += kb_[(size_t)d * Kn] * wq[(size_t)d * Cn + c];
    Mc[(size_t)(b * Cn + c) * Kn + k] = acc;
}

// ---------------------------------------------------------------------------
// e0[b,k] = sum_d bq[d] * kkt[b,d,k]
__global__ __launch_bounds__(256) void proj_e0_kernel(
    const float* __restrict__ kkt, const float* __restrict__ bq,
    float* __restrict__ e0)
{
    int idx = blockIdx.x * 256 + threadIdx.x;
    if (idx >= Bn * Kn) return;
    int k = idx & 63, b = idx >> 6;
    float acc = 0.f;
    #pragma unroll 8
    for (int d = 0; d < C4n; ++d)
        acc += bq[d] * kkt[(size_t)(b * C4n + d) * Kn + k];
    e0[idx] = acc;
}

// ---------------------------------------------------------------------------
// Fused: energy (via M) -> softmax(|.|) -> out1/out2 with scale+residual.
// One block per (b, 64-wide n-tile). 256 threads.
__global__ __launch_bounds__(256) void fused_attn_kernel(
    const float* __restrict__ x1, const float* __restrict__ x2,
    const float* __restrict__ pv1, const float* __restrict__ pv2,
    const float* __restrict__ Mc, const float* __restrict__ e0,
    const float* __restrict__ scale, const float* __restrict__ scale1,
    float* __restrict__ out1, float* __restrict__ out2)
{
    __shared__ float lds[13056];
    float* Xs    = lds;          // [32][68] phase E
    float* Mts   = lds + 4352;   // [32][68] phase E
    float* attsT = lds + 8704;   // [64][68] k-major attention, lives to end
    float* ps1   = lds;          // [64][68] phase O (reuses Xs region)
    float* ps2   = lds + 4352;   // [64][68] phase O (reuses Mts region)

    const int t  = threadIdx.x;
    const int b  = blockIdx.y;
    const int n0 = blockIdx.x * 64;

    // ---------------- Phase E: energy tile [64 n][64 k] ----------------
    const int kg = t & 15;       // k quad: k = 4*kg + j
    const int ng = t >> 4;       // n quad: n = 4*ng + i
    const int sc = t >> 3;       // staging row 0..31
    const int sb = (t & 7) * 8;  // staging col base

    float e[4][4] = {{0.f}};
    for (int c0 = 0; c0 < Cn; c0 += 32) {
        __syncthreads();
        {
            const float* xsrc = x2 + (size_t)(b * Cn + c0 + sc) * Nn + n0 + sb;
            float4 a0 = *(const float4*)xsrc;
            float4 a1 = *(const float4*)(xsrc + 4);
            const float* msrc = Mc + (size_t)(b * Cn + c0 + sc) * Kn + sb;
            float4 m0 = *(const float4*)msrc;
            float4 m1 = *(const float4*)(msrc + 4);
            *(float4*)&Xs[sc * 68 + sb]      = a0;
            *(float4*)&Xs[sc * 68 + sb + 4]  = a1;
            *(float4*)&Mts[sc * 68 + sb]     = m0;
            *(float4*)&Mts[sc * 68 + sb + 4] = m1;
        }
        __syncthreads();
        #pragma unroll 8
        for (int cc = 0; cc < 32; ++cc) {
            float4 xv = *(const float4*)&Xs[cc * 68 + 4 * ng];
            float4 mv = *(const float4*)&Mts[cc * 68 + 4 * kg];
            float xr[4] = {xv.x, xv.y, xv.z, xv.w};
            float mr[4] = {mv.x, mv.y, mv.z, mv.w};
            #pragma unroll
            for (int i = 0; i < 4; ++i)
                #pragma unroll
                for (int j = 0; j < 4; ++j)
                    e[i][j] += xr[i] * mr[j];
        }
    }

    // ---------------- softmax over k of |energy| ----------------
    {
        float4 ev = *(const float4*)&e0[b * Kn + 4 * kg];
        float e0r[4] = {ev.x, ev.y, ev.z, ev.w};
        #pragma unroll
        for (int i = 0; i < 4; ++i) {
            float a[4];
            #pragma unroll
            for (int j = 0; j < 4; ++j) a[j] = fabsf(e[i][j] + e0r[j]);
            float mx = fmaxf(fmaxf(a[0], a[1]), fmaxf(a[2], a[3]));
            #pragma unroll
            for (int m = 1; m <= 8; m <<= 1) mx = fmaxf(mx, __shfl_xor(mx, m));
            float s = 0.f;
            #pragma unroll
            for (int j = 0; j < 4; ++j) { a[j] = __expf(a[j] - mx); s += a[j]; }
            #pragma unroll
            for (int m = 1; m <= 8; m <<= 1) s += __shfl_xor(s, m);
            float inv = 1.0f / s;
            // write attsT[k][n] for k = 4*kg+j, n-local = 4*ng+i
            #pragma unroll
            for (int j = 0; j < 4; ++j) e[i][j] = a[j] * inv;  // reuse e as att
        }
        #pragma unroll
        for (int j = 0; j < 4; ++j) {
            float4 v;
            v.x = e[0][j]; v.y = e[1][j]; v.z = e[2][j]; v.w = e[3][j];
            *(float4*)&attsT[(4 * kg + j) * 68 + 4 * ng] = v;
        }
    }

    // ---------------- Phase O: out tiles, 8 passes of 64 c ----------------
    const float sA = scale[0], sB = scale1[0];
    const int nq = t & 15;      // n = 4*nq + m
    const int cg = t >> 4;      // c-local = 4*cg + i
    const int pc = t >> 2;      // staging row 0..63
    const int pk = (t & 3) * 16;
    for (int pass = 0; pass < 8; ++pass) {
        const int c0p = pass * 64;
        __syncthreads();   // attsT visible (pass 0); ps reusable (pass>0)
        {
            const float* s1 = pv1 + (size_t)(b * Cn + c0p + pc) * Kn + pk;
            const float* s2 = pv2 + (size_t)(b * Cn + c0p + pc) * Kn + pk;
            #pragma unroll
            for (int u = 0; u < 4; ++u) {
                *(float4*)&ps1[pc * 68 + pk + 4 * u] = *(const float4*)(s1 + 4 * u);
                *(float4*)&ps2[pc * 68 + pk + 4 * u] = *(const float4*)(s2 + 4 * u);
            }
        }
        __syncthreads();
        float acc1[4][4] = {{0.f}}, acc2[4][4] = {{0.f}};
        for (int kb = 0; kb < 64; kb += 4) {
            float a_[4][4], q1[4][4], q2[4][4];
            #pragma unroll
            for (int j = 0; j < 4; ++j) {
                float4 v = *(const float4*)&attsT[(kb + j) * 68 + 4 * nq];
                a_[j][0] = v.x; a_[j][1] = v.y; a_[j][2] = v.z; a_[j][3] = v.w;
            }
            #pragma unroll
            for (int i = 0; i < 4; ++i) {
                float4 v1 = *(const float4*)&ps1[(4 * cg + i) * 68 + kb];
                q1[i][0] = v1.x; q1[i][1] = v1.y; q1[i][2] = v1.z; q1[i][3] = v1.w;
                float4 v2 = *(const float4*)&ps2[(4 * cg + i) * 68 + kb];
                q2[i][0] = v2.x; q2[i][1] = v2.y; q2[i][2] = v2.z; q2[i][3] = v2.w;
            }
            #pragma unroll
            for (int i = 0; i < 4; ++i)
                #pragma unroll
                for (int j = 0; j < 4; ++j) {
                    float w1 = q1[i][j], w2 = q2[i][j];
                    #pragma unroll
                    for (int m = 0; m < 4; ++m) {
                        acc1[i][m] += w1 * a_[j][m];
                        acc2[i][m] += w2 * a_[j][m];
                    }
                }
        }
        #pragma unroll
        for (int i = 0; i < 4; ++i) {
            size_t row = (size_t)(b * Cn + c0p + 4 * cg + i) * Nn + n0 + 4 * nq;
            float4 xv1 = *(const float4*)&x1[row];
            float4 xv2 = *(const float4*)&x2[row];
            float4 o1, o2;
            o1.x = sA * acc1[i][0] + xv1.x;
            o1.y = sA * acc1[i][1] + xv1.y;
            o1.z = sA * acc1[i][2] + xv1.z;
            o1.w = sA * acc1[i][3] + xv1.w;
            o2.x = sB * acc2[i][0] + xv2.x;
            o2.y = sB * acc2[i][1] + xv2.y;
            o2.z = sB * acc2[i][2] + xv2.z;
            o2.w = sB * acc2[i][3] + xv2.w;
            *(float4*)&out1[row] = o1;
            *(float4*)&out2[row] = o2;
        }
    }
}

// ---------------------------------------------------------------------------
extern "C" void kernel_launch(void* const* d_in, const int* in_sizes, int n_in,
                              void* d_out, int out_size, void* d_ws, size_t ws_size,
                              hipStream_t stream)
{
    const float* x1     = (const float*)d_in[0];
    const float* y1     = (const float*)d_in[1];
    const float* x2     = (const float*)d_in[2];
    const float* y2     = (const float*)d_in[3];
    const float* wq     = (const float*)d_in[4];
    const float* bq     = (const float*)d_in[5];
    const float* wk     = (const float*)d_in[6];
    const float* bk     = (const float*)d_in[7];
    const float* wv     = (const float*)d_in[8];
    const float* bv     = (const float*)d_in[9];
    const float* scale  = (const float*)d_in[10];
    const float* scale1 = (const float*)d_in[11];

    float* out1 = (float*)d_out;
    float* out2 = out1 + (size_t)Bn * Cn * Nn;

    float* ws  = (float*)d_ws;
    float* pv1 = ws;                 // B*C*K = 262144
    float* pv2 = pv1 + 262144;       // 262144
    float* Mc  = pv2 + 262144;       // 262144
    float* kkt = Mc  + 262144;       // B*C4*K = 65536
    float* e0  = kkt + 65536;        // B*K = 512

    proj_pv_kernel<<<2048, 256, 0, stream>>>(y1, y2, wv, bv, pv1, pv2);
    proj_kkt_kernel<<<256, 256, 0, stream>>>(y2, wk, bk, kkt);
    proj_M_kernel<<<1024, 256, 0, stream>>>(kkt, wq, Mc);
    proj_e0_kernel<<<2, 256, 0, stream>>>(kkt, bq, e0);
    fused_attn_kernel<<<dim3(64, 8), 256, 0, stream>>>(
        x1, x2, pv1, pv2, Mc, e0, scale, scale1, out1, out2);
}

// Round 2
// 181.655 us; speedup vs baseline: 1.5649x; 1.5649x over previous
//
#include <hip/hip_runtime.h>
#include <math.h>

#define Bn 8
#define Cn 512
#define Kn 64
#define C4n 128
#define Nn 4096

// ---------------------------------------------------------------------------
// W2cm[c'][c] = sum_d wk[d,c'] * wq[d,c]          (contraction-major layout)
// m0[c]      = sum_d bk[d] * wq[d,c]
// wbv[c']    = sum_d bq[d] * wk[d,c'] ; wbv[512] = sum_d bq[d]*bk[d]
__global__ __launch_bounds__(256) void mk_W2_kernel(
    const float* __restrict__ wq, const float* __restrict__ wk,
    const float* __restrict__ bq, const float* __restrict__ bk,
    float* __restrict__ W2cm, float* __restrict__ m0, float* __restrict__ wbv)
{
    const int cp = blockIdx.x;          // c' in 0..511
    const int t  = threadIdx.x;
    float acc0 = 0.f, acc1 = 0.f;
    for (int d = 0; d < C4n; ++d) {
        float wkv = wk[(size_t)d * Cn + cp];     // uniform per block
        acc0 += wkv * wq[(size_t)d * Cn + t];
        acc1 += wkv * wq[(size_t)d * Cn + t + 256];
    }
    W2cm[(size_t)cp * Cn + t]       = acc0;
    W2cm[(size_t)cp * Cn + t + 256] = acc1;
    if (blockIdx.x == 0) {
        float a0 = 0.f, a1 = 0.f;
        for (int d = 0; d < C4n; ++d) {
            float bkv = bk[d];
            a0 += bkv * wq[(size_t)d * Cn + t];
            a1 += bkv * wq[(size_t)d * Cn + t + 256];
        }
        m0[t] = a0; m0[t + 256] = a1;
    }
    if (t == 0) {
        float a = 0.f;
        for (int d = 0; d < C4n; ++d) a += bq[d] * wk[(size_t)d * Cn + cp];
        wbv[cp] = a;
    }
    if (blockIdx.x == 0 && t == 0) {
        float a = 0.f;
        for (int d = 0; d < C4n; ++d) a += bq[d] * bk[d];
        wbv[512] = a;
    }
}

// ---------------------------------------------------------------------------
// wvT[c'][c] = wv[c][c']   (64x64 LDS tile transpose)
__global__ __launch_bounds__(256) void transpose_wv_kernel(
    const float* __restrict__ wv, float* __restrict__ wvT)
{
    __shared__ float tile[64 * 68];
    const int bx = blockIdx.x & 7;    // c' tile
    const int by = blockIdx.x >> 3;   // c  tile
    const int t  = threadIdx.x;
    {
        const int r  = t >> 2;
        const int cb = (t & 3) * 16;
        const float* src = wv + (size_t)(by * 64 + r) * Cn + bx * 64 + cb;
        #pragma unroll
        for (int u = 0; u < 4; ++u)
            *(float4*)&tile[r * 68 + cb + 4 * u] = *(const float4*)(src + 4 * u);
    }
    __syncthreads();
    {
        const int cpl = t >> 2;           // local c'
        const int cb  = (t & 3) * 16;     // local c base
        float* dst = wvT + (size_t)(bx * 64 + cpl) * Cn + by * 64 + cb;
        #pragma unroll
        for (int u = 0; u < 16; u += 4) {
            float4 v;
            v.x = tile[(cb + u + 0) * 68 + cpl];
            v.y = tile[(cb + u + 1) * 68 + cpl];
            v.z = tile[(cb + u + 2) * 68 + cpl];
            v.w = tile[(cb + u + 3) * 68 + cpl];
            *(float4*)(dst + u) = v;
        }
    }
}

// ---------------------------------------------------------------------------
// Batched tiled GEMM: out[b,c,k] = sum_c' W[c'][c] * y[b,k,c'] + bias[c]
// sel 0: (y1, wvT, bv)  -> pv1
// sel 1: (y2, wvT, bv)  -> pv2
// sel 2: (y2, W2cm, m0) -> Mc
__global__ __launch_bounds__(256) void proj_gemm_kernel(
    const float* __restrict__ y1, const float* __restrict__ y2,
    const float* __restrict__ wvT, const float* __restrict__ W2cm,
    const float* __restrict__ bv, const float* __restrict__ m0,
    float* __restrict__ pv1, float* __restrict__ pv2, float* __restrict__ Mc)
{
    __shared__ float Ws[32 * 68];
    __shared__ float Ys[32 * 68];
    const int sel = blockIdx.z;
    const int b   = blockIdx.y;
    const int ct  = blockIdx.x;     // c tile 0..7
    const float* y    = (sel == 0) ? y1 : y2;
    const float* W    = (sel == 2) ? W2cm : wvT;
    const float* bias = (sel == 2) ? m0 : bv;
    float* out = (sel == 0) ? pv1 : (sel == 1) ? pv2 : Mc;

    const int t   = threadIdx.x;
    const int wr  = t >> 3;          // Ws stage row (c')
    const int wcb = (t & 7) * 8;     // Ws stage col base (c-local)
    const int yk  = t >> 2;          // y stage row (k)
    const int ycb = (t & 3) * 8;     // y stage c' chunk base
    const int kq  = t & 15;          // output k quad
    const int cg  = t >> 4;          // output c quad

    float e[4][4] = {{0.f}};
    for (int c0 = 0; c0 < Cn; c0 += 32) {
        __syncthreads();
        {
            const float* wsrc = W + (size_t)(c0 + wr) * Cn + ct * 64 + wcb;
            float4 w0 = *(const float4*)wsrc;
            float4 w1 = *(const float4*)(wsrc + 4);
            *(float4*)&Ws[wr * 68 + wcb]     = w0;
            *(float4*)&Ws[wr * 68 + wcb + 4] = w1;
            const float* ysrc = y + (size_t)(b * Kn + yk) * Cn + c0 + ycb;
            float4 a0 = *(const float4*)ysrc;
            float4 a1 = *(const float4*)(ysrc + 4);
            Ys[(ycb + 0) * 68 + yk] = a0.x;
            Ys[(ycb + 1) * 68 + yk] = a0.y;
            Ys[(ycb + 2) * 68 + yk] = a0.z;
            Ys[(ycb + 3) * 68 + yk] = a0.w;
            Ys[(ycb + 4) * 68 + yk] = a1.x;
            Ys[(ycb + 5) * 68 + yk] = a1.y;
            Ys[(ycb + 6) * 68 + yk] = a1.z;
            Ys[(ycb + 7) * 68 + yk] = a1.w;
        }
        __syncthreads();
        #pragma unroll 8
        for (int cc = 0; cc < 32; ++cc) {
            float4 wv4 = *(const float4*)&Ws[cc * 68 + 4 * cg];
            float4 yv4 = *(const float4*)&Ys[cc * 68 + 4 * kq];
            float wr_[4] = {wv4.x, wv4.y, wv4.z, wv4.w};
            float yr_[4] = {yv4.x, yv4.y, yv4.z, yv4.w};
            #pragma unroll
            for (int i = 0; i < 4; ++i)
                #pragma unroll
                for (int j = 0; j < 4; ++j)
                    e[i][j] += wr_[i] * yr_[j];
        }
    }
    #pragma unroll
    for (int i = 0; i < 4; ++i) {
        int c = ct * 64 + 4 * cg + i;
        float bb = bias[c];
        float4 o;
        o.x = e[i][0] + bb; o.y = e[i][1] + bb;
        o.z = e[i][2] + bb; o.w = e[i][3] + bb;
        *(float4*)&out[(size_t)(b * Cn + c) * Kn + 4 * kq] = o;
    }
}

// ---------------------------------------------------------------------------
// e0[b,k] = sum_c' y2[b,k,c'] * wbv[c'] + wbv[512]
__global__ __launch_bounds__(256) void e0_kernel(
    const float* __restrict__ y2, const float* __restrict__ wbv,
    float* __restrict__ e0)
{
    int idx = blockIdx.x * 256 + threadIdx.x;
    if (idx >= Bn * Kn) return;
    int k = idx & 63, b = idx >> 6;
    const float* yr = y2 + (size_t)(b * Kn + k) * Cn;
    float acc = wbv[512];
    #pragma unroll 4
    for (int cc = 0; cc < Cn; cc += 4) {
        float4 yv = *(const float4*)(yr + cc);
        float4 wv4 = *(const float4*)(wbv + cc);
        acc += yv.x * wv4.x + yv.y * wv4.y + yv.z * wv4.z + yv.w * wv4.w;
    }
    e0[idx] = acc;
}

// ---------------------------------------------------------------------------
// Fused: energy (via M) -> softmax(|.|) -> out1/out2 with scale+residual.
// One block per (b, 64-wide n-tile). 256 threads.  (unchanged this round)
__global__ __launch_bounds__(256) void fused_attn_kernel(
    const float* __restrict__ x1, const float* __restrict__ x2,
    const float* __restrict__ pv1, const float* __restrict__ pv2,
    const float* __restrict__ Mc, const float* __restrict__ e0,
    const float* __restrict__ scale, const float* __restrict__ scale1,
    float* __restrict__ out1, float* __restrict__ out2)
{
    __shared__ float lds[13056];
    float* Xs    = lds;          // [32][68] phase E
    float* Mts   = lds + 4352;   // [32][68] phase E
    float* attsT = lds + 8704;   // [64][68] k-major attention, lives to end
    float* ps1   = lds;          // [64][68] phase O (reuses Xs region)
    float* ps2   = lds + 4352;   // [64][68] phase O (reuses Mts region)

    const int t  = threadIdx.x;
    const int b  = blockIdx.y;
    const int n0 = blockIdx.x * 64;

    // ---------------- Phase E: energy tile [64 n][64 k] ----------------
    const int kg = t & 15;       // k quad: k = 4*kg + j
    const int ng = t >> 4;       // n quad: n = 4*ng + i
    const int sc = t >> 3;       // staging row 0..31
    const int sb = (t & 7) * 8;  // staging col base

    float e[4][4] = {{0.f}};
    for (int c0 = 0; c0 < Cn; c0 += 32) {
        __syncthreads();
        {
            const float* xsrc = x2 + (size_t)(b * Cn + c0 + sc) * Nn + n0 + sb;
            float4 a0 = *(const float4*)xsrc;
            float4 a1 = *(const float4*)(xsrc + 4);
            const float* msrc = Mc + (size_t)(b * Cn + c0 + sc) * Kn + sb;
            float4 m0_ = *(const float4*)msrc;
            float4 m1_ = *(const float4*)(msrc + 4);
            *(float4*)&Xs[sc * 68 + sb]      = a0;
            *(float4*)&Xs[sc * 68 + sb + 4]  = a1;
            *(float4*)&Mts[sc * 68 + sb]     = m0_;
            *(float4*)&Mts[sc * 68 + sb + 4] = m1_;
        }
        __syncthreads();
        #pragma unroll 8
        for (int cc = 0; cc < 32; ++cc) {
            float4 xv = *(const float4*)&Xs[cc * 68 + 4 * ng];
            float4 mv = *(const float4*)&Mts[cc * 68 + 4 * kg];
            float xr[4] = {xv.x, xv.y, xv.z, xv.w};
            float mr[4] = {mv.x, mv.y, mv.z, mv.w};
            #pragma unroll
            for (int i = 0; i < 4; ++i)
                #pragma unroll
                for (int j = 0; j < 4; ++j)
                    e[i][j] += xr[i] * mr[j];
        }
    }

    // ---------------- softmax over k of |energy| ----------------
    {
        float4 ev = *(const float4*)&e0[b * Kn + 4 * kg];
        float e0r[4] = {ev.x, ev.y, ev.z, ev.w};
        #pragma unroll
        for (int i = 0; i < 4; ++i) {
            float a[4];
            #pragma unroll
            for (int j = 0; j < 4; ++j) a[j] = fabsf(e[i][j] + e0r[j]);
            float mx = fmaxf(fmaxf(a[0], a[1]), fmaxf(a[2], a[3]));
            #pragma unroll
            for (int m = 1; m <= 8; m <<= 1) mx = fmaxf(mx, __shfl_xor(mx, m));
            float s = 0.f;
            #pragma unroll
            for (int j = 0; j < 4; ++j) { a[j] = __expf(a[j] - mx); s += a[j]; }
            #pragma unroll
            for (int m = 1; m <= 8; m <<= 1) s += __shfl_xor(s, m);
            float inv = 1.0f / s;
            #pragma unroll
            for (int j = 0; j < 4; ++j) e[i][j] = a[j] * inv;  // reuse e as att
        }
        #pragma unroll
        for (int j = 0; j < 4; ++j) {
            float4 v;
            v.x = e[0][j]; v.y = e[1][j]; v.z = e[2][j]; v.w = e[3][j];
            *(float4*)&attsT[(4 * kg + j) * 68 + 4 * ng] = v;
        }
    }

    // ---------------- Phase O: out tiles, 8 passes of 64 c ----------------
    const float sA = scale[0], sB = scale1[0];
    const int nq = t & 15;      // n = 4*nq + m
    const int cg = t >> 4;      // c-local = 4*cg + i
    const int pc = t >> 2;      // staging row 0..63
    const int pk = (t & 3) * 16;
    for (int pass = 0; pass < 8; ++pass) {
        const int c0p = pass * 64;
        __syncthreads();   // attsT visible (pass 0); ps reusable (pass>0)
        {
            const float* s1 = pv1 + (size_t)(b * Cn + c0p + pc) * Kn + pk;
            const float* s2 = pv2 + (size_t)(b * Cn + c0p + pc) * Kn + pk;
            #pragma unroll
            for (int u = 0; u < 4; ++u) {
                *(float4*)&ps1[pc * 68 + pk + 4 * u] = *(const float4*)(s1 + 4 * u);
                *(float4*)&ps2[pc * 68 + pk + 4 * u] = *(const float4*)(s2 + 4 * u);
            }
        }
        __syncthreads();
        float acc1[4][4] = {{0.f}}, acc2[4][4] = {{0.f}};
        for (int kb = 0; kb < 64; kb += 4) {
            float a_[4][4], q1[4][4], q2[4][4];
            #pragma unroll
            for (int j = 0; j < 4; ++j) {
                float4 v = *(const float4*)&attsT[(kb + j) * 68 + 4 * nq];
                a_[j][0] = v.x; a_[j][1] = v.y; a_[j][2] = v.z; a_[j][3] = v.w;
            }
            #pragma unroll
            for (int i = 0; i < 4; ++i) {
                float4 v1 = *(const float4*)&ps1[(4 * cg + i) * 68 + kb];
                q1[i][0] = v1.x; q1[i][1] = v1.y; q1[i][2] = v1.z; q1[i][3] = v1.w;
                float4 v2 = *(const float4*)&ps2[(4 * cg + i) * 68 + kb];
                q2[i][0] = v2.x; q2[i][1] = v2.y; q2[i][2] = v2.z; q2[i][3] = v2.w;
            }
            #pragma unroll
            for (int i = 0; i < 4; ++i)
                #pragma unroll
                for (int j = 0; j < 4; ++j) {
                    float w1 = q1[i][j], w2 = q2[i][j];
                    #pragma unroll
                    for (int m = 0; m < 4; ++m) {
                        acc1[i][m] += w1 * a_[j][m];
                        acc2[i][m] += w2 * a_[j][m];
                    }
                }
        }
        #pragma unroll
        for (int i = 0; i < 4; ++i) {
            size_t row = (size_t)(b * Cn + c0p + 4 * cg + i) * Nn + n0 + 4 * nq;
            float4 xv1 = *(const float4*)&x1[row];
            float4 xv2 = *(const float4*)&x2[row];
            float4 o1, o2;
            o1.x = sA * acc1[i][0] + xv1.x;
            o1.y = sA * acc1[i][1] + xv1.y;
            o1.z = sA * acc1[i][2] + xv1.z;
            o1.w = sA * acc1[i][3] + xv1.w;
            o2.x = sB * acc2[i][0] + xv2.x;
            o2.y = sB * acc2[i][1] + xv2.y;
            o2.z = sB * acc2[i][2] + xv2.z;
            o2.w = sB * acc2[i][3] + xv2.w;
            *(float4*)&out1[row] = o1;
            *(float4*)&out2[row] = o2;
        }
    }
}

// ---------------------------------------------------------------------------
extern "C" void kernel_launch(void* const* d_in, const int* in_sizes, int n_in,
                              void* d_out, int out_size, void* d_ws, size_t ws_size,
                              hipStream_t stream)
{
    const float* x1     = (const float*)d_in[0];
    const float* y1     = (const float*)d_in[1];
    const float* x2     = (const float*)d_in[2];
    const float* y2     = (const float*)d_in[3];
    const float* wq     = (const float*)d_in[4];
    const float* bq     = (const float*)d_in[5];
    const float* wk     = (const float*)d_in[6];
    const float* bk     = (const float*)d_in[7];
    const float* wv     = (const float*)d_in[8];
    const float* bv     = (const float*)d_in[9];
    const float* scale  = (const float*)d_in[10];
    const float* scale1 = (const float*)d_in[11];

    float* out1 = (float*)d_out;
    float* out2 = out1 + (size_t)Bn * Cn * Nn;

    float* ws   = (float*)d_ws;
    float* pv1  = ws;                  // 262144
    float* pv2  = pv1 + 262144;        // 262144
    float* Mc   = pv2 + 262144;        // 262144
    float* wvT  = Mc  + 262144;        // 262144
    float* W2cm = wvT + 262144;        // 262144
    float* m0   = W2cm + 262144;       // 512
    float* wbv  = m0 + 512;            // 513
    float* e0   = wbv + 527;           // 512 (16B-aligned offset)

    mk_W2_kernel<<<512, 256, 0, stream>>>(wq, wk, bq, bk, W2cm, m0, wbv);
    transpose_wv_kernel<<<64, 256, 0, stream>>>(wv, wvT);
    proj_gemm_kernel<<<dim3(8, 8, 3), 256, 0, stream>>>(
        y1, y2, wvT, W2cm, bv, m0, pv1, pv2, Mc);
    e0_kernel<<<2, 256, 0, stream>>>(y2, wbv, e0);
    fused_attn_kernel<<<dim3(64, 8), 256, 0, stream>>>(
        x1, x2, pv1, pv2, Mc, e0, scale, scale1, out1, out2);
}

// Round 3
// 168.697 us; speedup vs baseline: 1.6851x; 1.0768x over previous
//
#include <hip/hip_runtime.h>
#include <math.h>

#define Bn 8
#define Cn 512
#define Kn 64
#define C4n 128
#define Nn 4096

typedef short bf16x8 __attribute__((ext_vector_type(8)));
typedef float f32x4  __attribute__((ext_vector_type(4)));
typedef unsigned short u16;

__device__ __forceinline__ u16 f2bf(float f) {
    union { float f; unsigned u; } v; v.f = f;
    unsigned r = v.u + 0x7FFF + ((v.u >> 16) & 1);   // RNE
    return (u16)(r >> 16);
}

// ---------------------------------------------------------------------------
// W2cm[c'][c] = sum_d wk[d,c'] * wq[d,c]
// m0[c]      = sum_d bk[d] * wq[d,c]
// wbv[c']    = sum_d bq[d] * wk[d,c'] ; wbv[512] = sum_d bq[d]*bk[d]
__global__ __launch_bounds__(256) void mk_W2_kernel(
    const float* __restrict__ wq, const float* __restrict__ wk,
    const float* __restrict__ bq, const float* __restrict__ bk,
    float* __restrict__ W2cm, float* __restrict__ m0, float* __restrict__ wbv)
{
    const int cp = blockIdx.x;
    const int t  = threadIdx.x;
    float acc0 = 0.f, acc1 = 0.f;
    for (int d = 0; d < C4n; ++d) {
        float wkv = wk[(size_t)d * Cn + cp];
        acc0 += wkv * wq[(size_t)d * Cn + t];
        acc1 += wkv * wq[(size_t)d * Cn + t + 256];
    }
    W2cm[(size_t)cp * Cn + t]       = acc0;
    W2cm[(size_t)cp * Cn + t + 256] = acc1;
    if (blockIdx.x == 0) {
        float a0 = 0.f, a1 = 0.f;
        for (int d = 0; d < C4n; ++d) {
            float bkv = bk[d];
            a0 += bkv * wq[(size_t)d * Cn + t];
            a1 += bkv * wq[(size_t)d * Cn + t + 256];
        }
        m0[t] = a0; m0[t + 256] = a1;
    }
    if (t == 0) {
        float a = 0.f;
        for (int d = 0; d < C4n; ++d) a += bq[d] * wk[(size_t)d * Cn + cp];
        wbv[cp] = a;
    }
    if (blockIdx.x == 0 && t == 0) {
        float a = 0.f;
        for (int d = 0; d < C4n; ++d) a += bq[d] * bk[d];
        wbv[512] = a;
    }
}

// ---------------------------------------------------------------------------
// wvT[c'][c] = wv[c][c']
__global__ __launch_bounds__(256) void transpose_wv_kernel(
    const float* __restrict__ wv, float* __restrict__ wvT)
{
    __shared__ float tile[64 * 68];
    const int bx = blockIdx.x & 7;
    const int by = blockIdx.x >> 3;
    const int t  = threadIdx.x;
    {
        const int r  = t >> 2;
        const int cb = (t & 3) * 16;
        const float* src = wv + (size_t)(by * 64 + r) * Cn + bx * 64 + cb;
        #pragma unroll
        for (int u = 0; u < 4; ++u)
            *(float4*)&tile[r * 68 + cb + 4 * u] = *(const float4*)(src + 4 * u);
    }
    __syncthreads();
    {
        const int cpl = t >> 2;
        const int cb  = (t & 3) * 16;
        float* dst = wvT + (size_t)(bx * 64 + cpl) * Cn + by * 64 + cb;
        #pragma unroll
        for (int u = 0; u < 16; u += 4) {
            float4 v;
            v.x = tile[(cb + u + 0) * 68 + cpl];
            v.y = tile[(cb + u + 1) * 68 + cpl];
            v.z = tile[(cb + u + 2) * 68 + cpl];
            v.w = tile[(cb + u + 3) * 68 + cpl];
            *(float4*)(dst + u) = v;
        }
    }
}

// ---------------------------------------------------------------------------
// Batched tiled GEMM: acc[c,k] = sum_c' W[c'][c] * y[b,k,c'] + bias[c]
// sel 0: (y1, wvT, bv)  -> pv1h[b][c][k]  bf16
// sel 1: (y2, wvT, bv)  -> pv2h[b][c][k]  bf16
// sel 2: (y2, W2cm, m0) -> Mth[b][k][c]   bf16 (transposed store)
__global__ __launch_bounds__(256) void proj_gemm_kernel(
    const float* __restrict__ y1, const float* __restrict__ y2,
    const float* __restrict__ wvT, const float* __restrict__ W2cm,
    const float* __restrict__ bv, const float* __restrict__ m0,
    u16* __restrict__ pv1h, u16* __restrict__ pv2h, u16* __restrict__ Mth)
{
    __shared__ float Ws[32 * 68];
    __shared__ float Ys[32 * 68];
    const int sel = blockIdx.z;
    const int b   = blockIdx.y;
    const int ct  = blockIdx.x;
    const float* y    = (sel == 0) ? y1 : y2;
    const float* W    = (sel == 2) ? W2cm : wvT;
    const float* bias = (sel == 2) ? m0 : bv;

    const int t   = threadIdx.x;
    const int wr  = t >> 3;
    const int wcb = (t & 7) * 8;
    const int yk  = t >> 2;
    const int ycb = (t & 3) * 8;
    const int kq  = t & 15;
    const int cg  = t >> 4;

    float e[4][4] = {{0.f}};
    for (int c0 = 0; c0 < Cn; c0 += 32) {
        __syncthreads();
        {
            const float* wsrc = W + (size_t)(c0 + wr) * Cn + ct * 64 + wcb;
            float4 w0 = *(const float4*)wsrc;
            float4 w1 = *(const float4*)(wsrc + 4);
            *(float4*)&Ws[wr * 68 + wcb]     = w0;
            *(float4*)&Ws[wr * 68 + wcb + 4] = w1;
            const float* ysrc = y + (size_t)(b * Kn + yk) * Cn + c0 + ycb;
            float4 a0 = *(const float4*)ysrc;
            float4 a1 = *(const float4*)(ysrc + 4);
            Ys[(ycb + 0) * 68 + yk] = a0.x;
            Ys[(ycb + 1) * 68 + yk] = a0.y;
            Ys[(ycb + 2) * 68 + yk] = a0.z;
            Ys[(ycb + 3) * 68 + yk] = a0.w;
            Ys[(ycb + 4) * 68 + yk] = a1.x;
            Ys[(ycb + 5) * 68 + yk] = a1.y;
            Ys[(ycb + 6) * 68 + yk] = a1.z;
            Ys[(ycb + 7) * 68 + yk] = a1.w;
        }
        __syncthreads();
        #pragma unroll 8
        for (int cc = 0; cc < 32; ++cc) {
            float4 wv4 = *(const float4*)&Ws[cc * 68 + 4 * cg];
            float4 yv4 = *(const float4*)&Ys[cc * 68 + 4 * kq];
            float wr_[4] = {wv4.x, wv4.y, wv4.z, wv4.w};
            float yr_[4] = {yv4.x, yv4.y, yv4.z, yv4.w};
            #pragma unroll
            for (int i = 0; i < 4; ++i)
                #pragma unroll
                for (int j = 0; j < 4; ++j)
                    e[i][j] += wr_[i] * yr_[j];
        }
    }
    if (sel < 2) {
        u16* out = sel ? pv2h : pv1h;
        #pragma unroll
        for (int i = 0; i < 4; ++i) {
            int c = ct * 64 + 4 * cg + i;
            float bb = bias[c];
            ushort4 o;
            o.x = f2bf(e[i][0] + bb); o.y = f2bf(e[i][1] + bb);
            o.z = f2bf(e[i][2] + bb); o.w = f2bf(e[i][3] + bb);
            *(ushort4*)&out[((size_t)(b * Cn + c) << 6) + 4 * kq] = o;
        }
    } else {
        int cbase = ct * 64 + 4 * cg;
        float b0 = bias[cbase], b1 = bias[cbase + 1];
        float b2 = bias[cbase + 2], b3 = bias[cbase + 3];
        #pragma unroll
        for (int j = 0; j < 4; ++j) {
            int k = 4 * kq + j;
            ushort4 o;
            o.x = f2bf(e[0][j] + b0); o.y = f2bf(e[1][j] + b1);
            o.z = f2bf(e[2][j] + b2); o.w = f2bf(e[3][j] + b3);
            *(ushort4*)&Mth[((size_t)(b * Kn + k) << 9) + cbase] = o;
        }
    }
}

// ---------------------------------------------------------------------------
// e0[b,k] = sum_c' y2[b,k,c'] * wbv[c'] + wbv[512]
__global__ __launch_bounds__(512) void e0_kernel(
    const float* __restrict__ y2, const float* __restrict__ wbv,
    float* __restrict__ e0)
{
    const int b = blockIdx.x;
    const int t = threadIdx.x;
    const int k = t >> 3;
    const int cb = (t & 7) * 64;
    const float* yr = y2 + (size_t)(b * Kn + k) * Cn + cb;
    const float* wr = wbv + cb;
    float acc = 0.f;
    #pragma unroll 4
    for (int i = 0; i < 64; i += 4) {
        float4 yv = *(const float4*)(yr + i);
        float4 wv4 = *(const float4*)(wr + i);
        acc += yv.x * wv4.x + yv.y * wv4.y + yv.z * wv4.z + yv.w * wv4.w;
    }
    acc += __shfl_xor(acc, 1);
    acc += __shfl_xor(acc, 2);
    acc += __shfl_xor(acc, 4);
    if ((t & 7) == 0) e0[b * Kn + k] = acc + wbv[512];
}

// ---------------------------------------------------------------------------
// Fused MFMA kernel: energy -> softmax(|.|) -> out1/out2 (scale+residual).
// Grid: 512 blocks (1-D), 256 threads. b = id&7 (XCD-affine), ntile = id>>3.
__global__ __launch_bounds__(256) void fused_attn_mfma(
    const float* __restrict__ x1, const float* __restrict__ x2,
    const u16* __restrict__ pv1h, const u16* __restrict__ pv2h,
    const u16* __restrict__ Mth, const float* __restrict__ e0,
    const float* __restrict__ scale, const float* __restrict__ scale1,
    float* __restrict__ out1, float* __restrict__ out2)
{
    __shared__ float Xs[32 * 68];
    __shared__ u16 attL[64 * 64];     // [n][k] bf16, 16B-chunk XOR swizzle

    const int id   = blockIdx.x;
    const int b    = id & 7;
    const int n0   = (id >> 3) * 64;
    const int t    = threadIdx.x;
    const int lane = t & 63;
    const int wid  = t >> 6;
    const int lr   = lane & 15;
    const int lg   = lane >> 4;

    // ---------------- Phase E: energy [64 n][64 k] via MFMA ----------------
    const int wn0 = wid * 16;
    f32x4 eacc[4];
    #pragma unroll
    for (int kt = 0; kt < 4; ++kt) eacc[kt] = (f32x4){0.f, 0.f, 0.f, 0.f};

    const int sc = t >> 3;
    const int sb = (t & 7) * 8;

    for (int c0 = 0; c0 < Cn; c0 += 32) {
        __syncthreads();
        {
            const float* src = x2 + (((size_t)(b * Cn + c0 + sc)) << 12) + n0 + sb;
            float4 a0 = *(const float4*)src;
            float4 a1 = *(const float4*)(src + 4);
            *(float4*)&Xs[sc * 68 + sb]     = a0;
            *(float4*)&Xs[sc * 68 + sb + 4] = a1;
        }
        __syncthreads();
        // A-frag: row n = wn0+lr, contraction c-off = lg*8+j (strided LDS + cvt)
        bf16x8 av;
        #pragma unroll
        for (int j = 0; j < 8; ++j)
            av[j] = (short)f2bf(Xs[(lg * 8 + j) * 68 + wn0 + lr]);
        // B-frags: col k = kt*16+lr, contraction c-off = lg*8+j (global bf16)
        const u16* mb = Mth + ((size_t)b << 15) + (size_t)lr * Cn + c0 + lg * 8;
        #pragma unroll
        for (int kt = 0; kt < 4; ++kt) {
            bf16x8 bv = *(const bf16x8*)(mb + ((size_t)kt << 13));
            eacc[kt] = __builtin_amdgcn_mfma_f32_16x16x32_bf16(av, bv, eacc[kt], 0, 0, 0);
        }
    }

    // ---------------- softmax over k of |energy + e0| ----------------
    {
        float e0v[4];
        #pragma unroll
        for (int kt = 0; kt < 4; ++kt) e0v[kt] = e0[b * Kn + lr + 16 * kt];
        #pragma unroll
        for (int reg = 0; reg < 4; ++reg) {
            float a[4];
            #pragma unroll
            for (int kt = 0; kt < 4; ++kt) a[kt] = fabsf(eacc[kt][reg] + e0v[kt]);
            float mx = fmaxf(fmaxf(a[0], a[1]), fmaxf(a[2], a[3]));
            #pragma unroll
            for (int m = 1; m <= 8; m <<= 1) mx = fmaxf(mx, __shfl_xor(mx, m));
            float s = 0.f;
            #pragma unroll
            for (int kt = 0; kt < 4; ++kt) { a[kt] = __expf(a[kt] - mx); s += a[kt]; }
            #pragma unroll
            for (int m = 1; m <= 8; m <<= 1) s += __shfl_xor(s, m);
            float inv = 1.0f / s;
            const int n = wn0 + lg * 4 + reg;
            #pragma unroll
            for (int kt = 0; kt < 4; ++kt) {
                int k = lr + 16 * kt;
                int addr = n * 64 + ((((k >> 3) ^ (n & 7)) << 3) | (k & 7));
                attL[addr] = f2bf(a[kt] * inv);
            }
        }
    }
    __syncthreads();

    // ---------------- Phase O: out[512 c][64 n] x2, MFMA ----------------
    bf16x8 bfr[4][2];
    #pragma unroll
    for (int nt = 0; nt < 4; ++nt)
        #pragma unroll
        for (int ks = 0; ks < 2; ++ks) {
            int nl = nt * 16 + lr;
            int chunk = (ks * 4 + lg) ^ (nl & 7);
            bfr[nt][ks] = *(const bf16x8*)&attL[nl * 64 + chunk * 8];
        }

    const float sA = scale[0], sB = scale1[0];
    const int wc0 = wid * 128;
    for (int ct = 0; ct < 8; ++ct) {
        const int cb = wc0 + ct * 16;
        const u16* p1 = pv1h + (((size_t)(b * Cn + cb + lr)) << 6) + lg * 8;
        const u16* p2 = pv2h + (((size_t)(b * Cn + cb + lr)) << 6) + lg * 8;
        bf16x8 a1[2], a2[2];
        a1[0] = *(const bf16x8*)p1;        a1[1] = *(const bf16x8*)(p1 + 32);
        a2[0] = *(const bf16x8*)p2;        a2[1] = *(const bf16x8*)(p2 + 32);
        #pragma unroll
        for (int nt = 0; nt < 4; ++nt) {
            f32x4 acc1 = (f32x4){0.f, 0.f, 0.f, 0.f};
            f32x4 acc2 = (f32x4){0.f, 0.f, 0.f, 0.f};
            acc1 = __builtin_amdgcn_mfma_f32_16x16x32_bf16(a1[0], bfr[nt][0], acc1, 0, 0, 0);
            acc1 = __builtin_amdgcn_mfma_f32_16x16x32_bf16(a1[1], bfr[nt][1], acc1, 0, 0, 0);
            acc2 = __builtin_amdgcn_mfma_f32_16x16x32_bf16(a2[0], bfr[nt][0], acc2, 0, 0, 0);
            acc2 = __builtin_amdgcn_mfma_f32_16x16x32_bf16(a2[1], bfr[nt][1], acc2, 0, 0, 0);
            #pragma unroll
            for (int reg = 0; reg < 4; ++reg) {
                size_t row = (((size_t)(b * Cn + cb + lg * 4 + reg)) << 12)
                             + n0 + nt * 16 + lr;
                out1[row] = sA * acc1[reg] + x1[row];
                out2[row] = sB * acc2[reg] + x2[row];
            }
        }
    }
}

// ---------------------------------------------------------------------------
extern "C" void kernel_launch(void* const* d_in, const int* in_sizes, int n_in,
                              void* d_out, int out_size, void* d_ws, size_t ws_size,
                              hipStream_t stream)
{
    const float* x1     = (const float*)d_in[0];
    const float* y1     = (const float*)d_in[1];
    const float* x2     = (const float*)d_in[2];
    const float* y2     = (const float*)d_in[3];
    const float* wq     = (const float*)d_in[4];
    const float* bq     = (const float*)d_in[5];
    const float* wk     = (const float*)d_in[6];
    const float* bk     = (const float*)d_in[7];
    const float* wv     = (const float*)d_in[8];
    const float* bv     = (const float*)d_in[9];
    const float* scale  = (const float*)d_in[10];
    const float* scale1 = (const float*)d_in[11];

    float* out1 = (float*)d_out;
    float* out2 = out1 + (size_t)Bn * Cn * Nn;

    float* ws    = (float*)d_ws;
    float* wvT   = ws;                     // 262144 f
    float* W2cm  = wvT + 262144;           // 262144 f
    float* m0    = W2cm + 262144;          // 512 f
    float* wbv   = m0 + 512;               // 520 f (513 used)
    float* e0    = wbv + 520;              // 512 f
    u16*   pv1h  = (u16*)(e0 + 512);       // 262144 u16
    u16*   pv2h  = pv1h + 262144;          // 262144 u16
    u16*   Mth   = pv2h + 262144;          // 262144 u16

    mk_W2_kernel<<<512, 256, 0, stream>>>(wq, wk, bq, bk, W2cm, m0, wbv);
    transpose_wv_kernel<<<64, 256, 0, stream>>>(wv, wvT);
    proj_gemm_kernel<<<dim3(8, 8, 3), 256, 0, stream>>>(
        y1, y2, wvT, W2cm, bv, m0, pv1h, pv2h, Mth);
    e0_kernel<<<Bn, 512, 0, stream>>>(y2, wbv, e0);
    fused_attn_mfma<<<512, 256, 0, stream>>>(
        x1, x2, pv1h, pv2h, Mth, e0, scale, scale1, out1, out2);
}